// Round 1
// baseline (783.909 us; speedup 1.0000x reference)
//
#include <hip/hip_runtime.h>
#include <hip/hip_bf16.h>
#include <math.h>

typedef __attribute__((ext_vector_type(8))) short bf16x8;
typedef __attribute__((ext_vector_type(4))) float f32x4;

#define NPH 257
#define KPAD 544          // 17 * 32
#define A_STRIDE 552      // bf16 elems; 1104 B -> 2-way LDS bank alias (free)
#define MAIN_LDS 140800

typedef const __attribute__((address_space(1))) void* gas_ptr;
typedef __attribute__((address_space(3))) void* las_ptr;

static __device__ __forceinline__ short f2bf(float f) {
    union { float f; unsigned u; } v; v.f = f;
    unsigned r = v.u + 0x7fffu + ((v.u >> 16) & 1u);
    return (short)(r >> 16);
}

// ---------------------------------------------------------------------------
// Kernel 1: Mt[j][kk] (bf16, [512][544]) = sum_d T[kk][d] * W[j][d]
//   kk <  257: T = scale_k *  cos(2*pi*k*d/512)
//   kk >= 257: T = scale_k * -sin(2*pi*k*d/512), k = kk-257
//   scale_k = 1/512 for k in {0,256}, else 2/512.  kk in [514,544) -> 0 pad.
// Inner loop uses a rotation recurrence (no trig), W row broadcast from LDS.
// ---------------------------------------------------------------------------
__global__ __launch_bounds__(576) void build_M(const float* __restrict__ W,
                                               short* __restrict__ Mt) {
    __shared__ float wrow[512];
    const int j = blockIdx.x;
    for (int d = threadIdx.x; d < 512; d += 576) wrow[d] = W[j * 512 + d];
    __syncthreads();
    const int kk = threadIdx.x;
    if (kk >= KPAD) return;
    float acc = 0.0f;
    if (kk < 2 * NPH) {
        const bool is_sin = (kk >= NPH);
        const int k = is_sin ? (kk - NPH) : kk;
        const float ang = 6.283185307179586f * (float)k * (1.0f / 512.0f);
        const float cD = cosf(ang), sD = sinf(ang);
        float cd = 1.0f, sd = 0.0f;
        if (is_sin) {
            for (int d = 0; d < 512; ++d) {
                acc = fmaf(sd, wrow[d], acc);
                float t = cd * cD - sd * sD;
                sd = fmaf(cd, sD, sd * cD);
                cd = t;
            }
        } else {
            for (int d = 0; d < 512; ++d) {
                acc = fmaf(cd, wrow[d], acc);
                float t = cd * cD - sd * sD;
                sd = fmaf(cd, sD, sd * cD);
                cd = t;
            }
        }
        float scale = (k == 0 || k == 256) ? (1.0f / 512.0f) : (2.0f / 512.0f);
        if (is_sin) scale = -scale;
        acc *= scale;
    }
    Mt[j * KPAD + kk] = f2bf(acc);
}

// ---------------------------------------------------------------------------
// Kernel 2: per block: 64 rows x 512 cols.
//   Phase A: A-panel [64][544] bf16 in LDS: cos/sin(2*pi*2*(x . theta))
//   K-loop : y = A @ Mt^T via mfma 16x16x32 bf16, double-buffered
//            global_load_lds staging of Mt k-slices.
//   Epilogue: fused LayerNorm (shfl + cross-wave LDS reduce), fp32 store.
// ---------------------------------------------------------------------------
__global__ __launch_bounds__(512, 2) void ssp_main(
    const float* __restrict__ x,
    const float* __restrict__ theta,
    const float* __restrict__ gamma,
    const short* __restrict__ Mt,
    float* __restrict__ out)
{
    extern __shared__ char lds[];
    short* Apan = (short*)lds;                       // 64*552*2 = 70656 B
    char* B0 = lds + 64 * A_STRIDE * 2;              // 32768 B
    char* B1 = B0 + 32768;                           // 32768 B
    float* redsum = (float*)(B1 + 32768);            // [64][8]
    float* redsq  = redsum + 512;                    // [64][8]
    float* muL    = redsq + 512;                     // [64]
    float* rsL    = muL + 64;                        // [64]

    const int tid  = threadIdx.x;
    const int lane = tid & 63;
    const int wave = tid >> 6;                       // 0..7
    const int row0 = blockIdx.x * 64;

    // ---- Phase A: build A panel ----
    {
        const int r  = tid >> 3;                     // 0..63
        const int l8 = tid & 7;
        const float4 xv = *(const float4*)(x + (size_t)(row0 + r) * 4);
        for (int jj = 0; jj < 33; ++jj) {
            int k = l8 + jj * 8;
            if (k < NPH) {
                float dot = xv.x * theta[k] + xv.y * theta[NPH + k]
                          + xv.z * theta[2 * NPH + k] + xv.w * theta[3 * NPH + k];
                float u = 2.0f * dot;                // phi = x . (theta/h), h=0.5
                float f = u - floorf(u);             // revolutions in [0,1)
                float ar = 6.2831853071795864f * f;
                float s = __sinf(ar);
                float c = __cosf(ar);
                Apan[r * A_STRIDE + k]       = f2bf(c);
                Apan[r * A_STRIDE + NPH + k] = f2bf(s);
            }
        }
        if (tid < 64) {                              // zero pad kk in [514,544)
            unsigned* p = (unsigned*)&Apan[tid * A_STRIDE + 514];
            #pragma unroll
            for (int i = 0; i < 15; ++i) p[i] = 0u;
        }
    }

    // ---- staging: slice ks (32 k's, all 512 j's) into buffer bptr ----
    // LDS layout: offset (h*512 + j)*16 holds Mt[j][ks*32 + h*8 .. +7]
    auto stage = [&](char* bptr, int ks) {
        const short* src = Mt + (size_t)tid * KPAD + ks * 32;
        #pragma unroll
        for (int i = 0; i < 4; ++i) {
            __builtin_amdgcn_global_load_lds(
                (gas_ptr)(const void*)(src + i * 8),
                (las_ptr)(void*)(bptr + (i * 512 + tid) * 16),
                16, 0, 0);
        }
    };

    stage(B0, 0);
    __syncthreads();   // drains vmcnt + covers A-panel writes

    f32x4 acc[4][4];
    #pragma unroll
    for (int m = 0; m < 4; ++m)
        #pragma unroll
        for (int n = 0; n < 4; ++n)
            acc[m][n] = (f32x4){0.f, 0.f, 0.f, 0.f};

    const int l15 = lane & 15;
    const int lh  = lane >> 4;                       // 0..3
    const int wcol = wave * 64;

    for (int t = 0; t < 17; ++t) {
        char* cur = (t & 1) ? B1 : B0;
        char* nxt = (t & 1) ? B0 : B1;
        if (t < 16) stage(nxt, t + 1);

        bf16x8 af[4], bfr[4];
        #pragma unroll
        for (int m = 0; m < 4; ++m) {
            const short* p = Apan + (m * 16 + l15) * A_STRIDE + t * 32 + lh * 8;
            af[m] = *(const bf16x8*)p;
        }
        #pragma unroll
        for (int n = 0; n < 4; ++n) {
            int j = wcol + n * 16 + l15;
            bfr[n] = *(const bf16x8*)(cur + (lh * 512 + j) * 16);
        }
        #pragma unroll
        for (int m = 0; m < 4; ++m)
            #pragma unroll
            for (int n = 0; n < 4; ++n)
                acc[m][n] = __builtin_amdgcn_mfma_f32_16x16x32_bf16(
                    af[m], bfr[n], acc[m][n], 0, 0, 0);
        __syncthreads();
    }

    // ---- fused LayerNorm ----
    #pragma unroll
    for (int m = 0; m < 4; ++m) {
        float ps[4] = {0.f, 0.f, 0.f, 0.f};
        float pq[4] = {0.f, 0.f, 0.f, 0.f};
        #pragma unroll
        for (int n = 0; n < 4; ++n)
            #pragma unroll
            for (int i = 0; i < 4; ++i) {
                float v = acc[m][n][i];
                ps[i] += v;
                pq[i] = fmaf(v, v, pq[i]);
            }
        #pragma unroll
        for (int off = 1; off < 16; off <<= 1)
            #pragma unroll
            for (int i = 0; i < 4; ++i) {
                ps[i] += __shfl_xor(ps[i], off);
                pq[i] += __shfl_xor(pq[i], off);
            }
        if (l15 == 0) {
            int rb = m * 16 + lh * 4;
            #pragma unroll
            for (int i = 0; i < 4; ++i) {
                redsum[(rb + i) * 8 + wave] = ps[i];
                redsq [(rb + i) * 8 + wave] = pq[i];
            }
        }
    }
    __syncthreads();
    if (tid < 64) {
        float s = 0.f, q = 0.f;
        #pragma unroll
        for (int w = 0; w < 8; ++w) { s += redsum[tid * 8 + w]; q += redsq[tid * 8 + w]; }
        float mu = s * (1.0f / 512.0f);
        float var = q * (1.0f / 512.0f) - mu * mu;
        muL[tid] = mu;
        rsL[tid] = rsqrtf(var + 1e-5f);
    }
    __syncthreads();

    float gm[4];
    #pragma unroll
    for (int n = 0; n < 4; ++n) gm[n] = gamma[wcol + n * 16 + l15];
    #pragma unroll
    for (int m = 0; m < 4; ++m)
        #pragma unroll
        for (int i = 0; i < 4; ++i) {
            int rl = m * 16 + lh * 4 + i;
            float mu = muL[rl];
            float rs = rsL[rl];
            size_t rowoff = (size_t)(row0 + rl) * 512;
            #pragma unroll
            for (int n = 0; n < 4; ++n) {
                float v = (acc[m][n][i] - mu) * rs * gm[n];
                out[rowoff + wcol + n * 16 + l15] = v;
            }
        }
}

extern "C" void kernel_launch(void* const* d_in, const int* in_sizes, int n_in,
                              void* d_out, int out_size, void* d_ws, size_t ws_size,
                              hipStream_t stream) {
    (void)in_sizes; (void)n_in; (void)out_size; (void)ws_size;
    const float* x     = (const float*)d_in[0];
    const float* theta = (const float*)d_in[1];
    const float* W     = (const float*)d_in[2];
    const float* gamma = (const float*)d_in[3];
    float* out = (float*)d_out;
    short* Mt  = (short*)d_ws;                       // 512*544*2 = 557056 B

    build_M<<<512, 576, 0, stream>>>(W, Mt);

    hipFuncSetAttribute(reinterpret_cast<const void*>(ssp_main),
                        hipFuncAttributeMaxDynamicSharedMemorySize, MAIN_LDS);
    ssp_main<<<4096, 512, MAIN_LDS, stream>>>(x, theta, gamma, Mt, out);
}

// Round 2
// 277.908 us; speedup vs baseline: 2.8207x; 2.8207x over previous
//
#include <hip/hip_runtime.h>
#include <hip/hip_bf16.h>
#include <math.h>

typedef __attribute__((ext_vector_type(8))) short bf16x8;
typedef __attribute__((ext_vector_type(4))) float f32x4;

#define NPH 257
#define SIN0 264          // sin block starts at kk=264 (16B-aligned)
#define KPAD 544          // 17 * 32
#define A_STRIDE 552      // bf16 elems; 1104 B stride
#define MAIN_LDS 79488

static __device__ __forceinline__ short f2bf(float f) {
    union { float f; unsigned u; } v; v.f = f;
    unsigned r = v.u + 0x7fffu + ((v.u >> 16) & 1u);
    return (short)(r >> 16);
}

// ---------------------------------------------------------------------------
// Kernel 1: Mt[j][kk] (bf16, [512][544]) = sum_d T[kk][d] * W[j][d]
//   kk <  257        : T = scale_k *  cos(2*pi*k*d/512), k = kk
//   264 <= kk < 521  : T = scale_k * -sin(2*pi*k*d/512), k = kk-264
//   else 0 (pads [257,264) and [521,544))
//   scale_k = 1/512 for k in {0,256}, else 2/512.
// ---------------------------------------------------------------------------
__global__ __launch_bounds__(576) void build_M(const float* __restrict__ W,
                                               short* __restrict__ Mt) {
    __shared__ float wrow[512];
    const int j = blockIdx.x;
    for (int d = threadIdx.x; d < 512; d += 576) wrow[d] = W[j * 512 + d];
    __syncthreads();
    const int kk = threadIdx.x;
    if (kk >= KPAD) return;
    float acc = 0.0f;
    int k = -1;
    bool is_sin = false;
    if (kk < NPH) { k = kk; }
    else if (kk >= SIN0 && kk < SIN0 + NPH) { k = kk - SIN0; is_sin = true; }
    if (k >= 0) {
        const float ang = 6.283185307179586f * (float)k * (1.0f / 512.0f);
        const float cD = cosf(ang), sD = sinf(ang);
        float cd = 1.0f, sd = 0.0f;
        if (is_sin) {
            for (int d = 0; d < 512; ++d) {
                acc = fmaf(sd, wrow[d], acc);
                float t = cd * cD - sd * sD;
                sd = fmaf(cd, sD, sd * cD);
                cd = t;
            }
        } else {
            for (int d = 0; d < 512; ++d) {
                acc = fmaf(cd, wrow[d], acc);
                float t = cd * cD - sd * sD;
                sd = fmaf(cd, sD, sd * cD);
                cd = t;
            }
        }
        float scale = (k == 0 || k == 256) ? (1.0f / 512.0f) : (2.0f / 512.0f);
        if (is_sin) scale = -scale;
        acc *= scale;
    }
    Mt[j * KPAD + kk] = f2bf(acc);
}

// ---------------------------------------------------------------------------
// Kernel 2: per block: 64 rows x 512 cols.
//   Phase A: A-panel [64][544] bf16 in LDS (cos | sin blocks), vectorized.
//   K-loop : barrier-free; B fragments loaded straight from L2-resident Mt,
//            A fragments from LDS, 16x16x32 bf16 MFMA, B prefetch t+1.
//   Epilogue: fused LayerNorm, fp32 store.
// ---------------------------------------------------------------------------
__global__ __launch_bounds__(512, 4) void ssp_main(
    const float* __restrict__ x,
    const float* __restrict__ theta,
    const float* __restrict__ gamma,
    const short* __restrict__ Mt,
    float* __restrict__ out)
{
    extern __shared__ char lds[];
    short* Apan   = (short*)lds;                     // 64*552*2 = 70656 B
    float* thetaL = (float*)(lds + 70656);           // 4*264*4  = 4224 B
    float* redsum = thetaL + 4 * 264;                // [64][8]
    float* redsq  = redsum + 512;                    // [64][8]
    float* muL    = redsq + 512;                     // [64]
    float* rsL    = muL + 64;                        // [64]

    const int tid  = threadIdx.x;
    const int lane = tid & 63;
    const int wave = tid >> 6;                       // 0..7
    const int row0 = blockIdx.x * 64;

    // stage theta -> LDS with aligned stride 264
    if (tid < NPH) {
        #pragma unroll
        for (int c = 0; c < 4; ++c)
            thetaL[c * 264 + tid] = theta[c * NPH + tid];
    }
    __syncthreads();

    // ---- Phase A: build A panel (8 threads per row, 8 phases per pass) ----
    {
        const int r  = tid >> 3;                     // 0..63
        const int l8 = tid & 7;
        const float4 xv = *(const float4*)(x + (size_t)(row0 + r) * 4);
        short* arow = Apan + r * A_STRIDE;

        #pragma unroll
        for (int pass = 0; pass < 4; ++pass) {
            const int k0 = pass * 64 + l8 * 8;
            union { float4 v[2]; float f[8]; } t0, t1, t2, t3;
            t0.v[0] = *(const float4*)(thetaL + 0 * 264 + k0);
            t0.v[1] = *(const float4*)(thetaL + 0 * 264 + k0 + 4);
            t1.v[0] = *(const float4*)(thetaL + 1 * 264 + k0);
            t1.v[1] = *(const float4*)(thetaL + 1 * 264 + k0 + 4);
            t2.v[0] = *(const float4*)(thetaL + 2 * 264 + k0);
            t2.v[1] = *(const float4*)(thetaL + 2 * 264 + k0 + 4);
            t3.v[0] = *(const float4*)(thetaL + 3 * 264 + k0);
            t3.v[1] = *(const float4*)(thetaL + 3 * 264 + k0 + 4);
            bf16x8 cv, sv;
            #pragma unroll
            for (int q = 0; q < 8; ++q) {
                float dot = xv.x * t0.f[q] + xv.y * t1.f[q]
                          + xv.z * t2.f[q] + xv.w * t3.f[q];
                float u = 2.0f * dot;                // phi = x . (theta/h), h=0.5
                float fr = u - floorf(u);
                float ar = 6.2831853071795864f * fr;
                float s, c;
                __sincosf(ar, &s, &c);
                cv[q] = f2bf(c);
                sv[q] = f2bf(s);
            }
            *(bf16x8*)(arow + k0)        = cv;
            *(bf16x8*)(arow + SIN0 + k0) = sv;
        }
        // edge k=256 + zero pads
        if (l8 == 0) {
            float dot = xv.x * thetaL[256] + xv.y * thetaL[264 + 256]
                      + xv.z * thetaL[2 * 264 + 256] + xv.w * thetaL[3 * 264 + 256];
            float u = 2.0f * dot;
            float fr = u - floorf(u);
            float ar = 6.2831853071795864f * fr;
            float s, c;
            __sincosf(ar, &s, &c);
            arow[256]        = f2bf(c);
            arow[SIN0 + 256] = f2bf(s);
        }
        if (l8 == 1) {
            #pragma unroll
            for (int i = NPH; i < SIN0; ++i) arow[i] = 0;
        }
        if (l8 == 2) {
            for (int i = SIN0 + NPH; i < KPAD; ++i) arow[i] = 0;
        }
    }
    __syncthreads();

    // ---- K-loop: barrier-free, B direct from global (L2-resident) ----
    const int l15 = lane & 15;
    const int lh  = lane >> 4;                       // 0..3
    const int wcol = wave * 64;

    const short* bp0 = Mt + (size_t)(wcol + 0 * 16 + l15) * KPAD + lh * 8;
    const short* bp1 = Mt + (size_t)(wcol + 1 * 16 + l15) * KPAD + lh * 8;
    const short* bp2 = Mt + (size_t)(wcol + 2 * 16 + l15) * KPAD + lh * 8;
    const short* bp3 = Mt + (size_t)(wcol + 3 * 16 + l15) * KPAD + lh * 8;
    const short* ap0 = Apan + l15 * A_STRIDE + lh * 8;

    f32x4 acc[4][4];
    #pragma unroll
    for (int m = 0; m < 4; ++m)
        #pragma unroll
        for (int n = 0; n < 4; ++n)
            acc[m][n] = (f32x4){0.f, 0.f, 0.f, 0.f};

    bf16x8 bcur[4], bnxt[4];
    bcur[0] = *(const bf16x8*)bp0;
    bcur[1] = *(const bf16x8*)bp1;
    bcur[2] = *(const bf16x8*)bp2;
    bcur[3] = *(const bf16x8*)bp3;

    for (int t = 0; t < 17; ++t) {
        if (t < 16) {
            const int off = (t + 1) * 32;
            bnxt[0] = *(const bf16x8*)(bp0 + off);
            bnxt[1] = *(const bf16x8*)(bp1 + off);
            bnxt[2] = *(const bf16x8*)(bp2 + off);
            bnxt[3] = *(const bf16x8*)(bp3 + off);
        }
        bf16x8 af[4];
        const short* ap = ap0 + t * 32;
        af[0] = *(const bf16x8*)(ap);
        af[1] = *(const bf16x8*)(ap + 16 * A_STRIDE);
        af[2] = *(const bf16x8*)(ap + 32 * A_STRIDE);
        af[3] = *(const bf16x8*)(ap + 48 * A_STRIDE);
        #pragma unroll
        for (int m = 0; m < 4; ++m)
            #pragma unroll
            for (int n = 0; n < 4; ++n)
                acc[m][n] = __builtin_amdgcn_mfma_f32_16x16x32_bf16(
                    af[m], bcur[n], acc[m][n], 0, 0, 0);
        bcur[0] = bnxt[0];
        bcur[1] = bnxt[1];
        bcur[2] = bnxt[2];
        bcur[3] = bnxt[3];
    }

    // ---- fused LayerNorm ----
    #pragma unroll
    for (int m = 0; m < 4; ++m) {
        float ps[4] = {0.f, 0.f, 0.f, 0.f};
        float pq[4] = {0.f, 0.f, 0.f, 0.f};
        #pragma unroll
        for (int n = 0; n < 4; ++n)
            #pragma unroll
            for (int i = 0; i < 4; ++i) {
                float v = acc[m][n][i];
                ps[i] += v;
                pq[i] = fmaf(v, v, pq[i]);
            }
        #pragma unroll
        for (int off = 1; off < 16; off <<= 1)
            #pragma unroll
            for (int i = 0; i < 4; ++i) {
                ps[i] += __shfl_xor(ps[i], off);
                pq[i] += __shfl_xor(pq[i], off);
            }
        if (l15 == 0) {
            int rb = m * 16 + lh * 4;
            #pragma unroll
            for (int i = 0; i < 4; ++i) {
                redsum[(rb + i) * 8 + wave] = ps[i];
                redsq [(rb + i) * 8 + wave] = pq[i];
            }
        }
    }
    __syncthreads();
    if (tid < 64) {
        float s = 0.f, q = 0.f;
        #pragma unroll
        for (int w = 0; w < 8; ++w) { s += redsum[tid * 8 + w]; q += redsq[tid * 8 + w]; }
        float mu = s * (1.0f / 512.0f);
        float var = q * (1.0f / 512.0f) - mu * mu;
        muL[tid] = mu;
        rsL[tid] = rsqrtf(var + 1e-5f);
    }
    __syncthreads();

    float gm[4];
    #pragma unroll
    for (int n = 0; n < 4; ++n) gm[n] = gamma[wcol + n * 16 + l15];
    #pragma unroll
    for (int m = 0; m < 4; ++m)
        #pragma unroll
        for (int i = 0; i < 4; ++i) {
            int rl = m * 16 + lh * 4 + i;
            float mu = muL[rl];
            float rs = rsL[rl];
            size_t rowoff = (size_t)(row0 + rl) * 512;
            #pragma unroll
            for (int n = 0; n < 4; ++n) {
                float v = (acc[m][n][i] - mu) * rs * gm[n];
                out[rowoff + wcol + n * 16 + l15] = v;
            }
        }
}

extern "C" void kernel_launch(void* const* d_in, const int* in_sizes, int n_in,
                              void* d_out, int out_size, void* d_ws, size_t ws_size,
                              hipStream_t stream) {
    (void)in_sizes; (void)n_in; (void)out_size; (void)ws_size;
    const float* x     = (const float*)d_in[0];
    const float* theta = (const float*)d_in[1];
    const float* W     = (const float*)d_in[2];
    const float* gamma = (const float*)d_in[3];
    float* out = (float*)d_out;
    short* Mt  = (short*)d_ws;                       // 512*544*2 = 557056 B

    build_M<<<512, 576, 0, stream>>>(W, Mt);

    hipFuncSetAttribute(reinterpret_cast<const void*>(ssp_main),
                        hipFuncAttributeMaxDynamicSharedMemorySize, MAIN_LDS);
    ssp_main<<<4096, 512, MAIN_LDS, stream>>>(x, theta, gamma, Mt, out);
}

// Round 4
// 269.282 us; speedup vs baseline: 2.9111x; 1.0320x over previous
//
#include <hip/hip_runtime.h>
#include <hip/hip_bf16.h>
#include <math.h>

typedef __attribute__((ext_vector_type(8))) short bf16x8;
typedef __attribute__((ext_vector_type(4))) float f32x4;

#define NPH 257
#define SIN0 264          // sin block starts at kk=264 (16B-aligned)
#define KPAD 544          // 17 * 32
#define A_STRIDE 552      // bf16 elems; 1104 B -> 2-way LDS bank alias (free)
#define MAIN_LDS 79488

static __device__ __forceinline__ short f2bf(float f) {
    union { float f; unsigned u; } v; v.f = f;
    unsigned r = v.u + 0x7fffu + ((v.u >> 16) & 1u);
    return (short)(r >> 16);
}

// ---------------------------------------------------------------------------
// Kernel 1: Mt[j][kk] (bf16, [512][544]) = sum_d T[kk][d] * W[j][d]
//   kk <  257        : T = scale_k *  cos(2*pi*k*d/512), k = kk
//   264 <= kk < 521  : T = scale_k * -sin(2*pi*k*d/512), k = kk-264
//   else 0.  scale_k = 1/512 for k in {0,256}, else 2/512.
// ---------------------------------------------------------------------------
__global__ __launch_bounds__(576) void build_M(const float* __restrict__ W,
                                               short* __restrict__ Mt) {
    __shared__ float wrow[512];
    const int j = blockIdx.x;
    for (int d = threadIdx.x; d < 512; d += 576) wrow[d] = W[j * 512 + d];
    __syncthreads();
    const int kk = threadIdx.x;
    if (kk >= KPAD) return;
    float acc = 0.0f;
    int k = -1;
    bool is_sin = false;
    if (kk < NPH) { k = kk; }
    else if (kk >= SIN0 && kk < SIN0 + NPH) { k = kk - SIN0; is_sin = true; }
    if (k >= 0) {
        const float ang = 6.283185307179586f * (float)k * (1.0f / 512.0f);
        const float cD = cosf(ang), sD = sinf(ang);
        float cd = 1.0f, sd = 0.0f;
        if (is_sin) {
            for (int d = 0; d < 512; ++d) {
                acc = fmaf(sd, wrow[d], acc);
                float t = cd * cD - sd * sD;
                sd = fmaf(cd, sD, sd * cD);
                cd = t;
            }
        } else {
            for (int d = 0; d < 512; ++d) {
                acc = fmaf(cd, wrow[d], acc);
                float t = cd * cD - sd * sD;
                sd = fmaf(cd, sD, sd * cD);
                cd = t;
            }
        }
        float scale = (k == 0 || k == 256) ? (1.0f / 512.0f) : (2.0f / 512.0f);
        if (is_sin) scale = -scale;
        acc *= scale;
    }
    Mt[j * KPAD + kk] = f2bf(acc);
}

// ---------------------------------------------------------------------------
// Kernel 2: per block: 64 rows x 512 cols.
// ---------------------------------------------------------------------------
__global__ __launch_bounds__(512, 4) void ssp_main(
    const float* __restrict__ x,
    const float* __restrict__ theta,
    const float* __restrict__ gamma,
    const short* __restrict__ Mt,
    float* __restrict__ out)
{
    extern __shared__ char lds[];
    short* Apan   = (short*)lds;                     // 64*552*2 = 70656 B
    float* thetaL = (float*)(lds + 70656);           // 4*264*4  = 4224 B
    float* redsum = thetaL + 4 * 264;                // [64][8]
    float* redsq  = redsum + 512;                    // [64][8]
    float* muL    = redsq + 512;                     // [64]
    float* rsL    = muL + 64;                        // [64]

    const int tid  = threadIdx.x;
    const int lane = tid & 63;
    const int wave = tid >> 6;                       // 0..7
    const int row0 = blockIdx.x * 64;

    const int l15 = lane & 15;
    const int lh  = lane >> 4;                       // 0..3
    const int wcol = wave * 64;

    // B-fragment base pointers (Mt is L2-resident: 544 KB)
    const short* bp[4];
    #pragma unroll
    for (int n = 0; n < 4; ++n)
        bp[n] = Mt + (size_t)(wcol + n * 16 + l15) * KPAD + lh * 8;

    // issue B load for t=0 NOW — latency hides under theta-stage + phase A
    bf16x8 bsA[4], bsB[4];
    #pragma unroll
    for (int n = 0; n < 4; ++n) bsA[n] = *(const bf16x8*)(bp[n]);

    // stage theta -> LDS with aligned stride 264
    if (tid < NPH) {
        #pragma unroll
        for (int c = 0; c < 4; ++c)
            thetaL[c * 264 + tid] = theta[c * NPH + tid];
    }
    __syncthreads();

    // ---- Phase A: build A panel (8 threads per row, 8 phases per pass) ----
    {
        const int r  = tid >> 3;                     // 0..63
        const int l8 = tid & 7;
        const float4 xv = *(const float4*)(x + (size_t)(row0 + r) * 4);
        short* arow = Apan + r * A_STRIDE;

        #pragma unroll
        for (int pass = 0; pass < 4; ++pass) {
            const int k0 = pass * 64 + l8 * 8;
            union { float4 v[2]; float f[8]; } t0, t1, t2, t3;
            t0.v[0] = *(const float4*)(thetaL + 0 * 264 + k0);
            t0.v[1] = *(const float4*)(thetaL + 0 * 264 + k0 + 4);
            t1.v[0] = *(const float4*)(thetaL + 1 * 264 + k0);
            t1.v[1] = *(const float4*)(thetaL + 1 * 264 + k0 + 4);
            t2.v[0] = *(const float4*)(thetaL + 2 * 264 + k0);
            t2.v[1] = *(const float4*)(thetaL + 2 * 264 + k0 + 4);
            t3.v[0] = *(const float4*)(thetaL + 3 * 264 + k0);
            t3.v[1] = *(const float4*)(thetaL + 3 * 264 + k0 + 4);
            bf16x8 cv, sv;
            #pragma unroll
            for (int q = 0; q < 8; ++q) {
                float dot = xv.x * t0.f[q] + xv.y * t1.f[q]
                          + xv.z * t2.f[q] + xv.w * t3.f[q];
                float u = 2.0f * dot;                // phi in revolutions
                float fr = u - floorf(u);
                cv[q] = f2bf(__builtin_amdgcn_cosf(fr));
                sv[q] = f2bf(__builtin_amdgcn_sinf(fr));
            }
            *(bf16x8*)(arow + k0)        = cv;
            *(bf16x8*)(arow + SIN0 + k0) = sv;
        }
        // edge k=256 + zero pads
        if (l8 == 0) {
            float dot = xv.x * thetaL[256] + xv.y * thetaL[264 + 256]
                      + xv.z * thetaL[2 * 264 + 256] + xv.w * thetaL[3 * 264 + 256];
            float u = 2.0f * dot;
            float fr = u - floorf(u);
            arow[256]        = f2bf(__builtin_amdgcn_cosf(fr));
            arow[SIN0 + 256] = f2bf(__builtin_amdgcn_sinf(fr));
        }
        if (l8 == 1) {
            #pragma unroll
            for (int i = NPH; i < SIN0; ++i) arow[i] = 0;
        }
        if (l8 == 2) {
            for (int i = SIN0 + NPH; i < KPAD; ++i) arow[i] = 0;
        }
    }
    __syncthreads();

    // ---- K-loop: depth-1 two-slot pipeline, consume-before-refill ----
    const short* ap0 = Apan + l15 * A_STRIDE + lh * 8;

    f32x4 acc[4][4];
    #pragma unroll
    for (int m = 0; m < 4; ++m)
        #pragma unroll
        for (int n = 0; n < 4; ++n)
            acc[m][n] = (f32x4){0.f, 0.f, 0.f, 0.f};

    #define LOAD_B(slot, t) { \
        const int off_ = (t) * 32; \
        slot[0] = *(const bf16x8*)(bp[0] + off_); \
        slot[1] = *(const bf16x8*)(bp[1] + off_); \
        slot[2] = *(const bf16x8*)(bp[2] + off_); \
        slot[3] = *(const bf16x8*)(bp[3] + off_); }

    #define DO_MFMA(slot, t) { \
        bf16x8 af[4]; \
        const short* ap_ = ap0 + (t) * 32; \
        af[0] = *(const bf16x8*)(ap_); \
        af[1] = *(const bf16x8*)(ap_ + 16 * A_STRIDE); \
        af[2] = *(const bf16x8*)(ap_ + 32 * A_STRIDE); \
        af[3] = *(const bf16x8*)(ap_ + 48 * A_STRIDE); \
        _Pragma("unroll") \
        for (int m = 0; m < 4; ++m) \
            _Pragma("unroll") \
            for (int n = 0; n < 4; ++n) \
                acc[m][n] = __builtin_amdgcn_mfma_f32_16x16x32_bf16( \
                    af[m], slot[n], acc[m][n], 0, 0, 0); }

    #pragma unroll
    for (int tt = 0; tt < 8; ++tt) {
        LOAD_B(bsB, 2 * tt + 1);
        DO_MFMA(bsA, 2 * tt);
        LOAD_B(bsA, 2 * tt + 2);
        DO_MFMA(bsB, 2 * tt + 1);
    }
    DO_MFMA(bsA, 16);

    #undef LOAD_B
    #undef DO_MFMA

    // ---- fused LayerNorm ----
    #pragma unroll
    for (int m = 0; m < 4; ++m) {
        float ps[4] = {0.f, 0.f, 0.f, 0.f};
        float pq[4] = {0.f, 0.f, 0.f, 0.f};
        #pragma unroll
        for (int n = 0; n < 4; ++n)
            #pragma unroll
            for (int i = 0; i < 4; ++i) {
                float v = acc[m][n][i];
                ps[i] += v;
                pq[i] = fmaf(v, v, pq[i]);
            }
        #pragma unroll
        for (int off = 1; off < 16; off <<= 1)
            #pragma unroll
            for (int i = 0; i < 4; ++i) {
                ps[i] += __shfl_xor(ps[i], off);
                pq[i] += __shfl_xor(pq[i], off);
            }
        if (l15 == 0) {
            int rb = m * 16 + lh * 4;
            #pragma unroll
            for (int i = 0; i < 4; ++i) {
                redsum[(rb + i) * 8 + wave] = ps[i];
                redsq [(rb + i) * 8 + wave] = pq[i];
            }
        }
    }
    __syncthreads();
    if (tid < 64) {
        float s = 0.f, q = 0.f;
        #pragma unroll
        for (int w = 0; w < 8; ++w) { s += redsum[tid * 8 + w]; q += redsq[tid * 8 + w]; }
        float mu = s * (1.0f / 512.0f);
        float var = q * (1.0f / 512.0f) - mu * mu;
        muL[tid] = mu;
        rsL[tid] = rsqrtf(var + 1e-5f);
    }
    __syncthreads();

    float gm[4];
    #pragma unroll
    for (int n = 0; n < 4; ++n) gm[n] = gamma[wcol + n * 16 + l15];
    #pragma unroll
    for (int m = 0; m < 4; ++m)
        #pragma unroll
        for (int i = 0; i < 4; ++i) {
            int rl = m * 16 + lh * 4 + i;
            float mu = muL[rl];
            float rs = rsL[rl];
            size_t rowoff = (size_t)(row0 + rl) * 512;
            #pragma unroll
            for (int n = 0; n < 4; ++n) {
                float v = (acc[m][n][i] - mu) * rs * gm[n];
                __builtin_nontemporal_store(v, &out[rowoff + wcol + n * 16 + l15]);
            }
        }
}

extern "C" void kernel_launch(void* const* d_in, const int* in_sizes, int n_in,
                              void* d_out, int out_size, void* d_ws, size_t ws_size,
                              hipStream_t stream) {
    (void)in_sizes; (void)n_in; (void)out_size; (void)ws_size;
    const float* x     = (const float*)d_in[0];
    const float* theta = (const float*)d_in[1];
    const float* W     = (const float*)d_in[2];
    const float* gamma = (const float*)d_in[3];
    float* out = (float*)d_out;
    short* Mt  = (short*)d_ws;                       // 512*544*2 = 557056 B

    build_M<<<512, 576, 0, stream>>>(W, Mt);

    hipFuncSetAttribute(reinterpret_cast<const void*>(ssp_main),
                        hipFuncAttributeMaxDynamicSharedMemorySize, MAIN_LDS);
    ssp_main<<<4096, 512, MAIN_LDS, stream>>>(x, theta, gamma, Mt, out);
}